// Round 6
// baseline (890.882 us; speedup 1.0000x reference)
//
#include <hip/hip_runtime.h>
#include <hip/hip_bf16.h>

typedef unsigned short u16;
typedef __attribute__((ext_vector_type(8))) short short8;
typedef __attribute__((ext_vector_type(4))) float float4v;

__device__ __forceinline__ u16 f2b(float f) {  // RNE f32->bf16 bits
    unsigned int u = __float_as_uint(f);
    return (u16)((u + 0x7fffu + ((u >> 16) & 1u)) >> 16);
}

#define MFMA(a, b, c) __builtin_amdgcn_mfma_f32_16x16x32_bf16((a), (b), (c), 0, 0, 0)

// ws layout (bf16): wqt[512][128]=Wq^T | wkvt[8][128][128]=per-head [Wk^T;Wv^T]
// | wot[128][512]=Wo^T.  All are B-operands (B^T row-major, contiguous K).
__global__ void prep_weights(const float* __restrict__ Wq,
                             const float* __restrict__ Wkv,
                             const float* __restrict__ Wo,
                             u16* __restrict__ ws)
{
    int t = blockIdx.x * 256 + threadIdx.x;   // 262144 total
    if (t < 65536) {
        int n = t >> 7, c = t & 127;
        ws[t] = f2b(Wq[c * 512 + n]);
    } else if (t < 196608) {
        int u = t - 65536;
        int h = u >> 14, r = (u >> 7) & 127, c = u & 127;
        float v = (r < 64) ? Wkv[c * 1024 + h * 64 + r]
                           : Wkv[c * 1024 + 512 + h * 64 + (r - 64)];
        ws[t] = f2b(v);
    } else {
        int u = t - 196608;
        int c = u >> 9, n = u & 511;
        ws[t] = f2b(Wo[n * 128 + c]);
    }
}

// WG = one (b, blk), 8 waves; wave w = head w end-to-end (flash streaming over
// j-tile pairs, zero barriers). Only 3 __syncthreads total: after x staging,
// around o_all handoff to the cooperative out-projection.
//
// LDS (dynamic, 153600 B), elem = u16:
//   x_sw [208][128] @0 (26624 el, XOR-swizzled chunks; rows 196..207 zero)
//   per-wave scratch @26624 + w*6272:
//     kq_t [16][72]  (0..1151)    q-transpose / k-transpose (sequential reuse)
//     v_pr [64][40]  (1152..3711) v^T[dv][pair-j]
//     p_pr [64][40]  (3712..6271) p[i][pair-j]
//   o_all [64][512] @0 (aliased over x_sw+scratch after barrier; XOR-swizzled)
__global__ __launch_bounds__(512, 2)
void halo_attn_mfma(const float* __restrict__ xg,
                    const u16* __restrict__ wqt,
                    const u16* __restrict__ wkvt,
                    const u16* __restrict__ wot,
                    const float* __restrict__ bo,
                    float* __restrict__ outg)
{
    extern __shared__ u16 lds[];
    u16* x_sw = lds;

    const int tid  = threadIdx.x;
    const int w    = tid >> 6;       // wave = head
    const int lane = tid & 63;
    const int m    = lane & 15;
    const int quad = lane >> 4;

    u16* scr  = lds + 26624 + w * 6272;   // kq_t [16][72]
    u16* v_pr = scr + 1152;               // [64][40]
    u16* p_pr = scr + 3712;               // [64][40]
    u16* o_all = lds;                     // [64][512] (aliased, post-barrier)

    const int wg  = blockIdx.x;
    const int b   = wg >> 8;
    const int blk = wg & 255;
    const int by = blk >> 4, bx = blk & 15;
    const int y0 = by * 8 - 3, x0 = bx * 8 - 3;

    const short8 zero8 = {0, 0, 0, 0, 0, 0, 0, 0};

    // ---- stage x window [pos][c] bf16, XOR-swizzled ----
    for (int job = tid; job < 3136; job += 512) {      // 16 c-chunks x 196 pos
        int cc  = job / 196;
        int pos = job - cc * 196;
        int wy = pos / 14;
        int wx = pos - wy * 14;
        int gy = y0 + wy, gx = x0 + wx;
        short8 pk = zero8;
        if ((unsigned)gy < 128u && (unsigned)gx < 128u) {
            const float* xp = xg + ((b * 128 + cc * 8) * 128 + gy) * 128 + gx;
#pragma unroll
            for (int r = 0; r < 8; ++r)
                pk[r] = (short)f2b(xp[r * 16384]);
        }
        *(short8*)(x_sw + pos * 128 + ((cc ^ (pos & 7)) << 3)) = pk;
    }
    for (int t = tid; t < 192; t += 512) {             // zero rows 196..207
        int row = 196 + (t >> 4), cc = t & 15;
        *(short8*)(x_sw + row * 128 + ((cc ^ (row & 7)) << 3)) = zero8;
    }
    __syncthreads();   // barrier 1: x_sw ready

    const int h = w;
    const u16* wkv_h = wkvt + h * 16384;

    // ===== q-proj: q[64 i][64 d], A-frags held in qa[it][kk] =====
    short8 qa[4][2];
    {
        short8 bq[4][4];
#pragma unroll
        for (int nt = 0; nt < 4; ++nt)
#pragma unroll
            for (int kk = 0; kk < 4; ++kk)
                bq[nt][kk] = *(const short8*)(wqt + (h * 64 + nt * 16 + m) * 128 +
                                              kk * 32 + quad * 8);
#pragma unroll 1
        for (int it = 0; it < 4; ++it) {
            int i = it * 16 + m;
            int jq = ((i >> 3) + 3) * 14 + (i & 7) + 3;
            float4v qc[4];
#pragma unroll
            for (int nt = 0; nt < 4; ++nt) qc[nt] = (float4v){0.f, 0.f, 0.f, 0.f};
#pragma unroll
            for (int kk = 0; kk < 4; ++kk) {
                short8 xa = *(const short8*)(x_sw + jq * 128 +
                                             (((kk * 4 + quad) ^ (jq & 7)) << 3));
#pragma unroll
                for (int nt = 0; nt < 4; ++nt) qc[nt] = MFMA(xa, bq[nt][kk], qc[nt]);
            }
#pragma unroll
            for (int nt = 0; nt < 4; ++nt)
#pragma unroll
                for (int r = 0; r < 4; ++r)
                    scr[(quad * 4 + r) * 72 + nt * 16 + m] = f2b(qc[nt][r] * 0.125f);
#pragma unroll
            for (int k2 = 0; k2 < 2; ++k2)
                qa[it][k2] = *(const short8*)(scr + m * 72 + k2 * 32 + quad * 8);
        }
    }

    // ===== flash loop over 7 j-tile pairs =====
    float4v o[4][4];
#pragma unroll
    for (int it = 0; it < 4; ++it)
#pragma unroll
        for (int nt = 0; nt < 4; ++nt) o[it][nt] = (float4v){0.f, 0.f, 0.f, 0.f};
    float lsum[4][4];
#pragma unroll
    for (int it = 0; it < 4; ++it)
#pragma unroll
        for (int r = 0; r < 4; ++r) lsum[it][r] = 0.f;

#pragma unroll 1
    for (int jp = 0; jp < 7; ++jp) {
#pragma unroll
        for (int half = 0; half < 2; ++half) {
            int t = jp * 2 + half;
            if (t < 13) {   // wave-uniform
                int row = t * 16 + m;
                short8 xa[4];
#pragma unroll
                for (int kk = 0; kk < 4; ++kk)
                    xa[kk] = *(const short8*)(x_sw + row * 128 +
                                              (((kk * 4 + quad) ^ (row & 7)) << 3));
                // k-proj -> kq_t
                float4v kc[4];
#pragma unroll
                for (int nt = 0; nt < 4; ++nt) kc[nt] = (float4v){0.f, 0.f, 0.f, 0.f};
#pragma unroll
                for (int kk = 0; kk < 4; ++kk)
#pragma unroll
                    for (int nt = 0; nt < 4; ++nt) {
                        short8 bk = *(const short8*)(wkv_h + (nt * 16 + m) * 128 +
                                                     kk * 32 + quad * 8);
                        kc[nt] = MFMA(xa[kk], bk, kc[nt]);
                    }
#pragma unroll
                for (int nt = 0; nt < 4; ++nt)
#pragma unroll
                    for (int r = 0; r < 4; ++r)
                        scr[(quad * 4 + r) * 72 + nt * 16 + m] = f2b(kc[nt][r]);
                // S: sim = q @ k^T
                short8 bks[2];
#pragma unroll
                for (int k2 = 0; k2 < 2; ++k2)
                    bks[k2] = *(const short8*)(scr + m * 72 + k2 * 32 + quad * 8);
                float4v sc[4];
#pragma unroll
                for (int it = 0; it < 4; ++it) {
                    sc[it] = (float4v){0.f, 0.f, 0.f, 0.f};
#pragma unroll
                    for (int k2 = 0; k2 < 2; ++k2)
                        sc[it] = MFMA(qa[it][k2], bks[k2], sc[it]);
                }
                // v-proj -> v_pr
                float4v vc[4];
#pragma unroll
                for (int nt = 0; nt < 4; ++nt) vc[nt] = (float4v){0.f, 0.f, 0.f, 0.f};
#pragma unroll
                for (int kk = 0; kk < 4; ++kk)
#pragma unroll
                    for (int nt = 0; nt < 4; ++nt) {
                        short8 bv = *(const short8*)(wkv_h + (64 + nt * 16 + m) * 128 +
                                                     kk * 32 + quad * 8);
                        vc[nt] = MFMA(xa[kk], bv, vc[nt]);
                    }
#pragma unroll
                for (int nt = 0; nt < 4; ++nt)
#pragma unroll
                    for (int r = 0; r < 4; ++r)
                        v_pr[(nt * 16 + m) * 40 + half * 16 + quad * 4 + r] = f2b(vc[nt][r]);
                // mask + exp (no max-subtract: |sim| << 88) -> p_pr
                int j = t * 16 + m;
                int wy = j / 14, wx = j - wy * 14;
                bool ok = (j < 196) && ((unsigned)(y0 + wy) < 128u) &&
                          ((unsigned)(x0 + wx) < 128u);
#pragma unroll
                for (int it = 0; it < 4; ++it)
#pragma unroll
                    for (int r = 0; r < 4; ++r) {
                        float p = ok ? __expf(sc[it][r]) : 0.f;
                        lsum[it][r] += p;
                        p_pr[(it * 16 + quad * 4 + r) * 40 + half * 16 + m] = f2b(p);
                    }
            } else {  // t == 13: p = 0 (stale v is finite; 0 * finite = 0)
#pragma unroll
                for (int it = 0; it < 4; ++it)
#pragma unroll
                    for (int r = 0; r < 4; ++r)
                        p_pr[(it * 16 + quad * 4 + r) * 40 + 16 + m] = 0;
            }
        }
        // PV for the pair (K = 32)
        short8 bvp[4];
#pragma unroll
        for (int nt = 0; nt < 4; ++nt)
            bvp[nt] = *(const short8*)(v_pr + (nt * 16 + m) * 40 + quad * 8);
#pragma unroll
        for (int it = 0; it < 4; ++it) {
            short8 pa = *(const short8*)(p_pr + (it * 16 + m) * 40 + quad * 8);
#pragma unroll
            for (int nt = 0; nt < 4; ++nt)
                o[it][nt] = MFMA(pa, bvp[nt], o[it][nt]);
        }
    }

    // ===== row-sum reduce over 16 j-lanes; fold 1/l ====
#pragma unroll
    for (int step = 1; step < 16; step <<= 1)
#pragma unroll
        for (int it = 0; it < 4; ++it)
#pragma unroll
            for (int r = 0; r < 4; ++r)
                lsum[it][r] += __shfl_xor(lsum[it][r], step, 64);
#pragma unroll
    for (int it = 0; it < 4; ++it)
#pragma unroll
        for (int r = 0; r < 4; ++r) lsum[it][r] = 1.f / lsum[it][r];

    __syncthreads();   // barrier 2: everyone done with x_sw/scratch

    // ---- write normalized o to o_all[64][512] (swizzled) ----
#pragma unroll
    for (int it = 0; it < 4; ++it)
#pragma unroll
        for (int nt = 0; nt < 4; ++nt)
#pragma unroll
            for (int r = 0; r < 4; ++r) {
                int i = it * 16 + quad * 4 + r;
                int col = h * 64 + nt * 16 + m;
                int ch = col >> 3;
                o_all[i * 512 + ((ch ^ (i & 7)) << 3) + (col & 7)] =
                    f2b(o[it][nt][r] * lsum[it][r]);
            }
    __syncthreads();   // barrier 3: o_all ready

    // ===== E: out = o_all @ Wo + bias; wave w -> it = w>>1, ct = (w&1)*4+tt =====
    {
        const int it_e = w >> 1;
        const int ct0 = (w & 1) * 4;
        short8 ae[16];
#pragma unroll
        for (int kk = 0; kk < 16; ++kk) {
            int ch = kk * 4 + quad;
            ae[kk] = *(const short8*)(o_all + (it_e * 16 + m) * 512 +
                                      ((ch ^ (m & 7)) << 3));
        }
#pragma unroll 1
        for (int tt = 0; tt < 4; ++tt) {
            int ct = ct0 + tt;
            float bias = bo[ct * 16 + m];
            float4v rc = {bias, bias, bias, bias};
#pragma unroll
            for (int kk = 0; kk < 16; ++kk) {
                short8 be = *(const short8*)(wot + (ct * 16 + m) * 512 +
                                             kk * 32 + quad * 8);
                rc = MFMA(ae[kk], be, rc);
            }
#pragma unroll
            for (int r = 0; r < 4; ++r) {
                int i = it_e * 16 + quad * 4 + r;
                int gy = by * 8 + (i >> 3), gx = bx * 8 + (i & 7);
                outg[((b * 128 + ct * 16 + m) * 128 + gy) * 128 + gx] = rc[r];
            }
        }
    }
}

extern "C" void kernel_launch(void* const* d_in, const int* in_sizes, int n_in,
                              void* d_out, int out_size, void* d_ws, size_t ws_size,
                              hipStream_t stream) {
    const float* x   = (const float*)d_in[0];
    const float* Wq  = (const float*)d_in[1];
    const float* Wkv = (const float*)d_in[2];
    const float* Wo  = (const float*)d_in[3];
    const float* bo  = (const float*)d_in[4];
    float* out = (float*)d_out;
    u16* ws = (u16*)d_ws;   // needs 512 KB

    prep_weights<<<dim3(1024), dim3(256), 0, stream>>>(Wq, Wkv, Wo, ws);

    (void)hipFuncSetAttribute((const void*)halo_attn_mfma,
                              hipFuncAttributeMaxDynamicSharedMemorySize, 153600);
    halo_attn_mfma<<<dim3(1024), dim3(512), 153600, stream>>>(
        x, ws, ws + 65536, ws + 196608, bo, out);
}

// Round 7
// 374.212 us; speedup vs baseline: 2.3807x; 2.3807x over previous
//
#include <hip/hip_runtime.h>
#include <hip/hip_bf16.h>

typedef unsigned short u16;
typedef __attribute__((ext_vector_type(8))) short short8;
typedef __attribute__((ext_vector_type(4))) short short4v;
typedef __attribute__((ext_vector_type(4))) float float4v;

__device__ __forceinline__ u16 f2b(float f) {  // RNE f32->bf16 bits
    unsigned int u = __float_as_uint(f);
    return (u16)((u + 0x7fffu + ((u >> 16) & 1u)) >> 16);
}

#define MFMA(a, b, c) __builtin_amdgcn_mfma_f32_16x16x32_bf16((a), (b), (c), 0, 0, 0)

// ws (u16): wqk[8][128][128] @0 : wqk[h][c][c0] = 0.125 * sum_d Wq[c0][h64+d]*Wk[c][h64+d]
//           wvt[8][64][128] @131072 : Wv_h^T[dv][c]
//           wot[128][512]   @196608 : Wo^T[cout][n]
__global__ void prep_weights(const float* __restrict__ Wq,
                             const float* __restrict__ Wkv,
                             const float* __restrict__ Wo,
                             u16* __restrict__ ws)
{
    const int bid = blockIdx.x, tid = threadIdx.x;
    if (bid < 32) {   // wqk: block = (h, 32-row group g)
        __shared__ float wq_s[128 * 65];
        __shared__ float wk_s[32 * 65];
        const int h = bid >> 2, g = bid & 3;
        for (int i = tid; i < 8192; i += 256) {
            int c0 = i >> 6, d = i & 63;
            wq_s[c0 * 65 + d] = Wq[c0 * 512 + h * 64 + d];
        }
        for (int i = tid; i < 2048; i += 256) {
            int cl = i >> 6, d = i & 63;
            wk_s[cl * 65 + d] = Wkv[(g * 32 + cl) * 1024 + h * 64 + d];
        }
        __syncthreads();
        const int c0 = tid & 127, clb = (tid >> 7) * 16;
        float acc[16];
#pragma unroll
        for (int cc = 0; cc < 16; ++cc) acc[cc] = 0.f;
        for (int d = 0; d < 64; ++d) {
            float a = wq_s[c0 * 65 + d];
#pragma unroll
            for (int cc = 0; cc < 16; ++cc)
                acc[cc] = fmaf(a, wk_s[(clb + cc) * 65 + d], acc[cc]);
        }
#pragma unroll
        for (int cc = 0; cc < 16; ++cc)
            ws[h * 16384 + (g * 32 + clb + cc) * 128 + c0] = f2b(0.125f * acc[cc]);
    } else {
        int idx = (bid - 32) * 256 + tid;
        if (idx < 65536) {                 // wvt
            int h = idx >> 13, c = (idx >> 6) & 127, dv = idx & 63;
            ws[131072 + h * 8192 + dv * 128 + c] =
                f2b(Wkv[c * 1024 + 512 + h * 64 + dv]);
        } else {                           // wot
            int j2 = idx - 65536;
            int cout = j2 >> 9, n = j2 & 511;
            ws[196608 + j2] = f2b(Wo[n * 128 + cout]);
        }
    }
}

// WG = 1024 threads (16 waves), one (b, blk). LDS (u16 el, odd*16B strides):
//   s_x  [208][136] @0      x window [pos][c], rows 196..207 zero
//   t_sw [64][136]  @28288  t = x_int @ Wqk_h
//   v_sw [64][232]  @36992  v^T[dv][j], chunks 26..28 zero
//   p_sw [64][232]  @51840  exp(sim)[i][j], chunks 26..28 zero
//   o_sw [64][72]   @66688  o[i][dv]
//   s_part[4][64] f32 @ byte 142592.  Total 143616 B -> 1 WG/CU.
__global__ __launch_bounds__(1024)
void halo_attn(const float* __restrict__ xg,
               const u16* __restrict__ wqk,
               const u16* __restrict__ wvt,
               const u16* __restrict__ wot,
               const float* __restrict__ bo,
               float* __restrict__ outg)
{
    extern __shared__ u16 lds[];
    u16* s_x  = lds;
    u16* t_sw = lds + 28288;
    u16* v_sw = lds + 36992;
    u16* p_sw = lds + 51840;
    u16* o_sw = lds + 66688;
    float* s_part = (float*)((char*)lds + 142592);

    const int tid  = threadIdx.x;
    const int w    = tid >> 6;
    const int lane = tid & 63;
    const int m    = lane & 15;
    const int quad = lane >> 4;

    // XCD-swizzle: 128 consecutive logical blocks per XCD (halo L2 reuse)
    const int wg = (blockIdx.x >> 3) + (blockIdx.x & 7) * 128;
    const int b   = wg >> 8;
    const int blk = wg & 255;
    const int by = blk >> 4, bx = blk & 15;
    const int y0 = by * 8 - 3, x0 = bx * 8 - 3;

    const short8 zero8 = {0, 0, 0, 0, 0, 0, 0, 0};

    // ---- stage x window [pos][c] bf16 ----
    for (int job = tid; job < 208 * 16; job += 1024) {
        int row = job >> 4, cc = job & 15;
        short8 pk = zero8;
        if (row < 196) {
            int wy = row / 14, wx = row - wy * 14;
            int gy = y0 + wy, gx = x0 + wx;
            if ((unsigned)gy < 128u && (unsigned)gx < 128u) {
                const float* xp = xg + ((b * 128 + cc * 8) * 128 + gy) * 128 + gx;
#pragma unroll
                for (int r = 0; r < 8; ++r)
                    pk[r] = (short)f2b(xp[r * 16384]);
            }
        }
        *(short8*)(s_x + row * 136 + cc * 8) = pk;
    }
    // zero v/p pad chunks 26..28 (j = 208..231)
    for (int t = tid; t < 384; t += 1024) {
        int half = t / 192, u = t - half * 192;
        int r = u / 3, ch = 26 + (u - r * 3);
        u16* base = half ? p_sw : v_sw;
        *(short8*)(base + r * 232 + ch * 8) = zero8;
    }
    __syncthreads();

    float4v res[2];
    res[0] = (float4v){0.f, 0.f, 0.f, 0.f};
    res[1] = (float4v){0.f, 0.f, 0.f, 0.f};

    for (int h = 0; h < 8; ++h) {
        // ===== Phase T (waves 0..3) + V (waves 4..15) =====
        if (w < 4) {
            // T: t = x_int @ Wqk_h ; wave owns ct = {2w, 2w+1}
            short8 bq[2][4];
#pragma unroll
            for (int p2 = 0; p2 < 2; ++p2)
#pragma unroll
                for (int kk = 0; kk < 4; ++kk)
                    bq[p2][kk] = *(const short8*)(wqk + h * 16384 +
                                 ((2 * w + p2) * 16 + m) * 128 + kk * 32 + quad * 8);
#pragma unroll 1
            for (int it = 0; it < 4; ++it) {
                int i = it * 16 + m;
                int jq = ((i >> 3) + 3) * 14 + (i & 7) + 3;
                short8 xa[4];
#pragma unroll
                for (int kk = 0; kk < 4; ++kk)
                    xa[kk] = *(const short8*)(s_x + jq * 136 + kk * 32 + quad * 8);
#pragma unroll
                for (int p2 = 0; p2 < 2; ++p2) {
                    float4v c = {0.f, 0.f, 0.f, 0.f};
#pragma unroll
                    for (int kk = 0; kk < 4; ++kk) c = MFMA(xa[kk], bq[p2][kk], c);
#pragma unroll
                    for (int r = 0; r < 4; ++r)
                        t_sw[(it * 16 + quad * 4 + r) * 136 + (2 * w + p2) * 16 + m]
                            = f2b(c[r]);
                }
            }
        } else {
            // V: v = x_win @ Wv_h ; wave (nt = u&3, sub = u>>2): jts {0-4|5-8|9-12}
            const int u = w - 4;
            const int nt = u & 3, sub = u >> 2;
            const int start = sub ? (1 + 4 * sub) : 0;
            const int count = sub ? 4 : 5;
            short8 bv[4];
#pragma unroll
            for (int kk = 0; kk < 4; ++kk)
                bv[kk] = *(const short8*)(wvt + h * 8192 + (nt * 16 + m) * 128 +
                                          kk * 32 + quad * 8);
#pragma unroll 1
            for (int jj = 0; jj < count; ++jj) {
                int jt = start + jj;
                float4v c = {0.f, 0.f, 0.f, 0.f};
#pragma unroll
                for (int kk = 0; kk < 4; ++kk) {
                    short8 xa = *(const short8*)(s_x + (jt * 16 + m) * 136 +
                                                 kk * 32 + quad * 8);
                    c = MFMA(xa, bv[kk], c);
                }
                short4v pk;
#pragma unroll
                for (int r = 0; r < 4; ++r) pk[r] = (short)f2b(c[r]);
                *(short4v*)(v_sw + (nt * 16 + m) * 232 + jt * 16 + quad * 4) = pk;
            }
        }
        __syncthreads();   // barrier 1: t, v ready

        // ===== Phase S: sim = t @ x_win^T, exp (no max), partial row-sums =====
        {
            const int it = w & 3, q4 = w >> 2;
            const int start = q4 ? (1 + 3 * q4) : 0;   // {0-3 | 4-6 | 7-9 | 10-12}
            const int count = q4 ? 3 : 4;
            short8 ta[4];
#pragma unroll
            for (int kk = 0; kk < 4; ++kk)
                ta[kk] = *(const short8*)(t_sw + (it * 16 + m) * 136 +
                                          kk * 32 + quad * 8);
            float lsum[4] = {0.f, 0.f, 0.f, 0.f};
#pragma unroll 1
            for (int jj = 0; jj < count; ++jj) {
                int jt = start + jj;
                float4v c = {0.f, 0.f, 0.f, 0.f};
#pragma unroll
                for (int kk = 0; kk < 4; ++kk) {
                    short8 xb = *(const short8*)(s_x + (jt * 16 + m) * 136 +
                                                 kk * 32 + quad * 8);
                    c = MFMA(ta[kk], xb, c);
                }
                int j = jt * 16 + m;
                int wy = j / 14, wx = j - wy * 14;
                bool ok = (j < 196) && ((unsigned)(y0 + wy) < 128u) &&
                          ((unsigned)(x0 + wx) < 128u);
#pragma unroll
                for (int r = 0; r < 4; ++r) {
                    float p = ok ? __expf(c[r]) : 0.f;
                    lsum[r] += p;
                    p_sw[(it * 16 + quad * 4 + r) * 232 + j] = f2b(p);
                }
            }
#pragma unroll
            for (int mk = 1; mk < 16; mk <<= 1)
#pragma unroll
                for (int r = 0; r < 4; ++r)
                    lsum[r] += __shfl_xor(lsum[r], mk, 64);
            if (m == 0) {
#pragma unroll
                for (int r = 0; r < 4; ++r)
                    s_part[q4 * 64 + it * 16 + quad * 4 + r] = lsum[r];
            }
        }
        __syncthreads();   // barrier 2: p, partial sums ready

        // ===== Phase PV: o = p @ v^T (K=224), normalize -> o_sw =====
        {
            const int it = w & 3, nt = w >> 2;
            float4v c = {0.f, 0.f, 0.f, 0.f};
#pragma unroll
            for (int kk = 0; kk < 7; ++kk) {
                short8 pa = *(const short8*)(p_sw + (it * 16 + m) * 232 +
                                             kk * 32 + quad * 8);
                short8 vb = *(const short8*)(v_sw + (nt * 16 + m) * 232 +
                                             kk * 32 + quad * 8);
                c = MFMA(pa, vb, c);
            }
#pragma unroll
            for (int r = 0; r < 4; ++r) {
                int i = it * 16 + quad * 4 + r;
                float ss = s_part[i] + s_part[64 + i] + s_part[128 + i] + s_part[192 + i];
                o_sw[i * 72 + nt * 16 + m] = f2b(c[r] / ss);
            }
        }
        __syncthreads();   // barrier 3: o ready

        // ===== Phase E: res += o @ Wo_h (no barrier after) =====
        {
            const int ct = w & 7, itp = w >> 3;
            short8 bw[2];
#pragma unroll
            for (int kk = 0; kk < 2; ++kk)
                bw[kk] = *(const short8*)(wot + (ct * 16 + m) * 512 + h * 64 +
                                          kk * 32 + quad * 8);
#pragma unroll
            for (int t2 = 0; t2 < 2; ++t2) {
                int it = itp * 2 + t2;
                float4v c = res[t2];
#pragma unroll
                for (int kk = 0; kk < 2; ++kk) {
                    short8 ao = *(const short8*)(o_sw + (it * 16 + m) * 72 +
                                                 kk * 32 + quad * 8);
                    c = MFMA(ao, bw[kk], c);
                }
                res[t2] = c;
            }
        }
    } // heads

    // ---- store fp32 out[b][ch][gy][gx] ----
    {
        const int ct = w & 7, itp = w >> 3;
        const int ch = ct * 16 + m;
        const float bias = bo[ch];
#pragma unroll
        for (int t2 = 0; t2 < 2; ++t2) {
#pragma unroll
            for (int r = 0; r < 4; ++r) {
                int i = (itp * 2 + t2) * 16 + quad * 4 + r;
                int gy = by * 8 + (i >> 3), gx = bx * 8 + (i & 7);
                outg[((b * 128 + ch) * 128 + gy) * 128 + gx] = res[t2][r] + bias;
            }
        }
    }
}

extern "C" void kernel_launch(void* const* d_in, const int* in_sizes, int n_in,
                              void* d_out, int out_size, void* d_ws, size_t ws_size,
                              hipStream_t stream) {
    const float* x   = (const float*)d_in[0];
    const float* Wq  = (const float*)d_in[1];
    const float* Wkv = (const float*)d_in[2];
    const float* Wo  = (const float*)d_in[3];
    const float* bo  = (const float*)d_in[4];
    float* out = (float*)d_out;
    u16* ws = (u16*)d_ws;   // needs 512 KB

    prep_weights<<<dim3(544), dim3(256), 0, stream>>>(Wq, Wkv, Wo, ws);

    (void)hipFuncSetAttribute((const void*)halo_attn,
                              hipFuncAttributeMaxDynamicSharedMemorySize, 143616);
    halo_attn<<<dim3(1024), dim3(1024), 143616, stream>>>(
        x, ws, ws + 131072, ws + 196608, bo, out);
}